// Round 10
// baseline (296.246 us; speedup 1.0000x reference)
//
#include <hip/hip_runtime.h>
#include <math.h>

#define DH 128
#define BCAP 8192   // slots per 256-node bucket: raw edges mean ~4096 (64 sigma);
                    // padded csr mean ~6270 (~15 sigma). Clamp degrades gracefully.

typedef __bf16 bf8_t __attribute__((ext_vector_type(8)));
typedef short short8 __attribute__((ext_vector_type(8)));
typedef float f4_t __attribute__((ext_vector_type(4)));
typedef float f2_t __attribute__((ext_vector_type(2)));

__device__ inline unsigned short f2b(float f) {
    unsigned int u = __builtin_bit_cast(unsigned int, f);
    u = u + 0x7fffu + ((u >> 16) & 1u);  // RNE
    return (unsigned short)(u >> 16);
}
__device__ inline float b2f(unsigned short h) {
    return __builtin_bit_cast(float, (unsigned int)h << 16);
}

// ---------- Pass A: bucket edges by dst>>8 (782 blocks) + fused W-prep blocks ----------
// Blocks [0, ablocks): bucket chunk of 2048 edges into 256-node buckets.
// Blocks [ablocks, ablocks+128): W prep (independent work, saves one launch):
//   Wt1[n][k] = bf16(W1[k][n]); Wt2[n][p(k)] = bf16(W2[k][n]), p(k)=((k&15)<<3)|(k>>4)
//   (layer-2 k-order permuted to match k_agg's permuted activation bytes);
//   plus zeroing the fp8 table's sentinel row (t8 is NOT aliased with pairs).
__global__ __launch_bounds__(256) void k_bucket(const int* __restrict__ row,
                                                const int* __restrict__ col,
                                                int E, int nbuck, int chunk, int ablocks,
                                                unsigned int* __restrict__ pairs,
                                                int* __restrict__ bcur,
                                                const float* __restrict__ W1,
                                                const float* __restrict__ W2,
                                                unsigned short* __restrict__ Wt1,
                                                unsigned short* __restrict__ Wt2,
                                                unsigned int* __restrict__ t8zrow) {
    int t = threadIdx.x;
    if ((int)blockIdx.x >= ablocks) {
        int bid2 = (int)blockIdx.x - ablocks;
        int g = bid2 * 256 + t;               // 0..32767
        if (bid2 == 0 && t < 32) t8zrow[t] = 0u;
        int v = g & 16383;
        int k = v >> 7, n = v & 127;
        if (g < 16384) {
            Wt1[n * DH + k] = f2b(W1[k * DH + n]);
        } else {
            int p = ((k & 15) << 3) | (k >> 4);
            Wt2[n * DH + p] = f2b(W2[k * DH + n]);
        }
        return;
    }
    __shared__ int lcnt[400];
    __shared__ int lbase[400];
    __shared__ unsigned int srec[2048];
    int e0 = blockIdx.x * chunk;
    int e1 = min(e0 + chunk, E);
    for (int i = t; i < nbuck; i += 256) lcnt[i] = 0;
    __syncthreads();
    for (int i = e0 + t; i < e1; i += 256) {
        int d = col[i];
        int b = d >> 8;
        int slot = atomicAdd(&lcnt[b], 1);
        // b:9 | dl:8 | slot:11  (slot < chunk = 2048)
        srec[i - e0] = ((unsigned int)b << 19) | ((unsigned int)(d & 255) << 11)
                     | (unsigned int)slot;
    }
    __syncthreads();
    for (int bb = t; bb < nbuck; bb += 256) {
        int c = lcnt[bb];
        lbase[bb] = (c > 0) ? atomicAdd(&bcur[bb * 16], c) : 0;  // stride 16: 1 line/counter
    }
    __syncthreads();
    for (int i = e0 + t; i < e1; i += 256) {
        unsigned int r = srec[i - e0];
        int b = r >> 19;
        unsigned int dl = (r >> 11) & 255u;
        int slot = (int)(r & 2047u);
        int g = lbase[b] + slot;
        if (g < BCAP)
            pairs[(size_t)b * BCAP + g] = ((unsigned int)row[i] << 8) | dl;
    }
}

// ---------- Pass B: per-bucket build (256 nodes, 512 threads), monolithic ----------
// Bucket-local scatter (one block owns one csr region -> one L2, no cross-XCD
// write amplification -- r7 lesson). Runs = [self, edges..., sentinels...]
// padded to x16 with sentinel index N (zero table row). dinv = rsqrt(deg+1).
__global__ __launch_bounds__(512) void k_build(const unsigned int* __restrict__ pairs,
                                               const int* __restrict__ bcur,
                                               int nbuck, int N,
                                               int* __restrict__ off,
                                               int* __restrict__ dpd,
                                               float* __restrict__ dinv,
                                               int* __restrict__ csr) {
    __shared__ int cnt2[256];
    __shared__ int scn[256];
    __shared__ int curi[256];
    int b = blockIdx.x, t = threadIdx.x;
    int cnt = min(bcur[b * 16], BCAP);
    int base = b * BCAP;           // bucket-strided csr region
    int node0 = b << 8;
    int nodes = min(256, N - node0);
    if (t < 256) cnt2[t] = (t < nodes) ? 1 : 0;   // seed self edge
    __syncthreads();
    const unsigned int* pp = pairs + (size_t)b * BCAP;
    for (int i = t; i < cnt; i += 512)
        atomicAdd(&cnt2[pp[i] & 255u], 1);
    __syncthreads();
    if (t < 256) { int pdv = (cnt2[t] + 15) & ~15; scn[t] = pdv; }
    __syncthreads();
    for (int d = 1; d < 256; d <<= 1) {           // Hillis-Steele inclusive scan
        int v = (t < 256 && t >= d) ? scn[t - d] : 0;
        __syncthreads();
        if (t < 256) scn[t] += v;
        __syncthreads();
    }
    if (t < 256) {
        int c = cnt2[t];                          // 1 + indegree (0 for t>=nodes)
        int pdv = (c + 15) & ~15;
        int exc = min(scn[t] - pdv, BCAP);        // exclusive prefix (mult of 16)
        int avail = BCAP - exc;
        int pdc = min(pdv, avail);                // monotone clamp (~never fires)
        curi[t] = exc + 1;                        // scatter starts after self edge
        if (t < nodes) {
            off[node0 + t] = base + exc;
            dpd[node0 + t] = pdc;
            dinv[node0 + t] = rsqrtf((float)c);
            if (pdc > 0) csr[base + exc] = node0 + t;                 // self edge
            for (int k = c; k < pdc; k++) csr[base + exc + k] = N;    // sentinels
        }
    }
    __syncthreads();
    for (int i = t; i < cnt; i += 512) {
        unsigned int p = pp[i];
        int d = (int)(p & 255u);
        int slot = atomicAdd(&curi[d], 1);
        if (slot < BCAP) csr[base + slot] = (int)(p >> 8);
    }
}

// ---------- MFMA GEMM -> fp8 e4m3 table, lane-major permuted rows ----------
__global__ __launch_bounds__(256) void k_gemm_mfma(const void* __restrict__ Xin, int x_is_bf16,
                                                   const unsigned short* __restrict__ Wt,
                                                   const float* __restrict__ dinv,
                                                   unsigned char* __restrict__ Y, int nrows) {
    __shared__ unsigned short Xs[64 * 136];
    __shared__ unsigned short Ws[128 * 136];
    int t = threadIdx.x;
    int row0 = blockIdx.x * 64;

    for (int v = t; v < 128 * 32; v += 256) {
        int n = v >> 5, kq = v & 31;
        ushort4 w = ((const ushort4*)Wt)[v];
        *(ushort4*)&Ws[n * 136 + kq * 4] = w;
    }
    if (x_is_bf16) {
        const unsigned short* X = (const unsigned short*)Xin;
        for (int v = t; v < 64 * 32; v += 256) {
            int r = v >> 5, cq = v & 31;
            int gr = row0 + r;
            ushort4 h;
            if (gr < nrows) h = ((const ushort4*)X)[(size_t)gr * 32 + cq];
            else { h.x = 0; h.y = 0; h.z = 0; h.w = 0; }
            *(ushort4*)&Xs[r * 136 + cq * 4] = h;
        }
    } else {
        const float* X = (const float*)Xin;
        for (int v = t; v < 64 * 32; v += 256) {
            int r = v >> 5, cq = v & 31;
            int gr = row0 + r;
            ushort4 h;
            if (gr < nrows) {
                float4 xv = ((const float4*)X)[(size_t)gr * 32 + cq];
                h.x = f2b(xv.x); h.y = f2b(xv.y); h.z = f2b(xv.z); h.w = f2b(xv.w);
            } else { h.x = 0; h.y = 0; h.z = 0; h.w = 0; }
            *(ushort4*)&Xs[r * 136 + cq * 4] = h;
        }
    }
    __syncthreads();

    int w = t >> 6;
    int lane = t & 63;
    int quad = lane >> 4;
    int l16 = lane & 15;
    int rw = w * 16;

    f4_t acc[8];
#pragma unroll
    for (int j = 0; j < 8; j++) acc[j] = (f4_t){0.f, 0.f, 0.f, 0.f};

#pragma unroll
    for (int kk = 0; kk < 4; kk++) {
        int k0 = kk * 32;
        bf8_t a = __builtin_bit_cast(bf8_t,
            *(const short8*)&Xs[(rw + l16) * 136 + k0 + quad * 8]);
#pragma unroll
        for (int j = 0; j < 8; j++) {
            bf8_t b = __builtin_bit_cast(bf8_t,
                *(const short8*)&Ws[(j * 16 + l16) * 136 + k0 + quad * 8]);
            acc[j] = __builtin_amdgcn_mfma_f32_16x16x32_bf16(a, b, acc[j], 0, 0, 0);
        }
    }

#pragma unroll
    for (int reg = 0; reg < 4; reg++) {
        int r = row0 + rw + quad * 4 + reg;
        if (r < nrows) {
            float dv = dinv[r];
            float v0 = acc[0][reg] * dv, v1 = acc[1][reg] * dv;
            float v2 = acc[2][reg] * dv, v3 = acc[3][reg] * dv;
            float v4 = acc[4][reg] * dv, v5 = acc[5][reg] * dv;
            float v6 = acc[6][reg] * dv, v7 = acc[7][reg] * dv;
            int d0 = __builtin_amdgcn_cvt_pk_fp8_f32(v0, v1, 0, false);
            d0 = __builtin_amdgcn_cvt_pk_fp8_f32(v2, v3, d0, true);
            int d1 = __builtin_amdgcn_cvt_pk_fp8_f32(v4, v5, 0, false);
            d1 = __builtin_amdgcn_cvt_pk_fp8_f32(v6, v7, d1, true);
            *(uint2*)&Y[(size_t)r * DH + l16 * 8] = make_uint2((unsigned)d0, (unsigned)d1);
        }
    }
}

// ---------- Gather core: 8-deep unmasked round ----------
#define AGG_ROUND(IDX)                                                     \
    {                                                                      \
        int ea = be + i;                                                   \
        unsigned v0 = ((unsigned)IDX(ea)     << 7) | l5b;                  \
        unsigned v1 = ((unsigned)IDX(ea + 1) << 7) | l5b;                  \
        unsigned v2 = ((unsigned)IDX(ea + 2) << 7) | l5b;                  \
        unsigned v3 = ((unsigned)IDX(ea + 3) << 7) | l5b;                  \
        unsigned v4 = ((unsigned)IDX(ea + 4) << 7) | l5b;                  \
        unsigned v5 = ((unsigned)IDX(ea + 5) << 7) | l5b;                  \
        unsigned v6 = ((unsigned)IDX(ea + 6) << 7) | l5b;                  \
        unsigned v7 = ((unsigned)IDX(ea + 7) << 7) | l5b;                  \
        unsigned int u0 = *(const unsigned int*)(Tb + v0);                 \
        unsigned int u1 = *(const unsigned int*)(Tb + v1);                 \
        unsigned int u2 = *(const unsigned int*)(Tb + v2);                 \
        unsigned int u3 = *(const unsigned int*)(Tb + v3);                 \
        unsigned int u4 = *(const unsigned int*)(Tb + v4);                 \
        unsigned int u5 = *(const unsigned int*)(Tb + v5);                 \
        unsigned int u6 = *(const unsigned int*)(Tb + v6);                 \
        unsigned int u7 = *(const unsigned int*)(Tb + v7);                 \
        accA01 += __builtin_amdgcn_cvt_pk_f32_fp8(u0, false);              \
        accA23 += __builtin_amdgcn_cvt_pk_f32_fp8(u0, true);               \
        accB01 += __builtin_amdgcn_cvt_pk_f32_fp8(u1, false);              \
        accB23 += __builtin_amdgcn_cvt_pk_f32_fp8(u1, true);               \
        accA01 += __builtin_amdgcn_cvt_pk_f32_fp8(u2, false);              \
        accA23 += __builtin_amdgcn_cvt_pk_f32_fp8(u2, true);               \
        accB01 += __builtin_amdgcn_cvt_pk_f32_fp8(u3, false);              \
        accB23 += __builtin_amdgcn_cvt_pk_f32_fp8(u3, true);               \
        accA01 += __builtin_amdgcn_cvt_pk_f32_fp8(u4, false);              \
        accA23 += __builtin_amdgcn_cvt_pk_f32_fp8(u4, true);               \
        accB01 += __builtin_amdgcn_cvt_pk_f32_fp8(u5, false);              \
        accB23 += __builtin_amdgcn_cvt_pk_f32_fp8(u5, true);               \
        accA01 += __builtin_amdgcn_cvt_pk_f32_fp8(u6, false);              \
        accA23 += __builtin_amdgcn_cvt_pk_f32_fp8(u6, true);               \
        accB01 += __builtin_amdgcn_cvt_pk_f32_fp8(u7, false);              \
        accB23 += __builtin_amdgcn_cvt_pk_f32_fp8(u7, true);               \
    }

// ---------- Gather-accumulate aggregation (round-5 proven form, unchanged) ----------
__global__ __launch_bounds__(256) void k_agg(const unsigned char* __restrict__ T,
                                             unsigned short* __restrict__ Out,
                                             const float* __restrict__ dinv,
                                             const int* __restrict__ off,
                                             const int* __restrict__ dpd,
                                             const int* __restrict__ csr,
                                             const float* __restrict__ bias,
                                             int elu, int N) {
    __shared__ int ofs[16];
    __shared__ int pds[16];
    __shared__ float dv16[16];
    __shared__ int sidx[768];
    int t = threadIdx.x;
    int d0 = blockIdx.x * 16;
    if (t < 16) {
        int n = min(d0 + t, N - 1);
        ofs[t] = off[n];
        pds[t] = dpd[n];
        dv16[t] = dinv[n];
    }
    __syncthreads();
    int s0 = ofs[0];
    int span = ofs[15] + pds[15] - s0;  // contiguous: 16 | 256, same bucket
    int scnt = min(span, 768);
    for (int k = t; k < scnt; k += 256) sidx[k] = csr[s0 + k];
    __syncthreads();

    int w = t >> 6;
    int lane = t & 63;
    int half = lane >> 5;
    int l5 = lane & 31;
    unsigned l5b = (unsigned)(l5 << 2);
    const char* Tb = (const char*)T;

    // permuted slot p = 4*l5+b holds true col 64*(l5&1) + 16*b + (l5>>1)
    int c0 = ((l5 & 1) << 6) | (l5 >> 1);
    float bb0 = bias[c0], bb1 = bias[c0 + 16], bb2 = bias[c0 + 32], bb3 = bias[c0 + 48];

    for (int ni = 0; ni < 4; ni++) {
        int nl = 4 * w + ni;
        int nd = d0 + nl;
        if (nd >= N) break;
        int eL = ofs[nl] - s0;
        int pd = pds[nl];
        int K = pd >> 1;           // per-half run; multiple of 8
        int be = eL + half * K;    // contiguous half

        f2_t accA01 = (f2_t){0.f, 0.f}, accA23 = (f2_t){0.f, 0.f};
        f2_t accB01 = (f2_t){0.f, 0.f}, accB23 = (f2_t){0.f, 0.f};

        if (eL + pd <= scnt) {
#define IDX_L(e) sidx[e]
            for (int i = 0; i < K; i += 8) AGG_ROUND(IDX_L)
#undef IDX_L
        } else {
            const int* gp = csr + s0;   // rare: slice > 768 (staging overflow)
#define IDX_G(e) gp[e]
            for (int i = 0; i < K; i += 8) AGG_ROUND(IDX_G)
#undef IDX_G
        }

        float a0 = accA01[0] + accB01[0];
        float a1 = accA01[1] + accB01[1];
        float a2 = accA23[0] + accB23[0];
        float a3 = accA23[1] + accB23[1];
        a0 += __shfl_xor(a0, 32);
        a1 += __shfl_xor(a1, 32);
        a2 += __shfl_xor(a2, 32);
        a3 += __shfl_xor(a3, 32);

        if (!half) {
            float dv = dv16[nl];
            float o0 = a0 * dv + bb0;
            float o1 = a1 * dv + bb1;
            float o2 = a2 * dv + bb2;
            float o3 = a3 * dv + bb3;
            if (elu) {
                o0 = o0 > 0.f ? o0 : __expf(o0) - 1.f;
                o1 = o1 > 0.f ? o1 : __expf(o1) - 1.f;
                o2 = o2 > 0.f ? o2 : __expf(o2) - 1.f;
                o3 = o3 > 0.f ? o3 : __expf(o3) - 1.f;
            }
            unsigned int p0 = (unsigned int)f2b(o0) | ((unsigned int)f2b(o1) << 16);
            unsigned int p1 = (unsigned int)f2b(o2) | ((unsigned int)f2b(o3) << 16);
            *(uint2*)&Out[(size_t)nd * DH + (l5 << 2)] = make_uint2(p0, p1);
        }
    }
}

// ---------- Mean pool: wave-per-row streaming, (G x 32) blocks, bf16 input ----------
// Input rows are in permuted byte order; Gsum stays permuted (k_head fixes).
__global__ __launch_bounds__(256) void k_pool(const unsigned int* __restrict__ H32,
                                              const int* __restrict__ batch,
                                              float* __restrict__ Gsum,
                                              int* __restrict__ cnts, int N) {
    int g = blockIdx.x;
    int p = blockIdx.y;
    int t = threadIdx.x;
    int lane = t & 63;
    int rg = t >> 6;  // wave 0..3
    int lo = 0, hi = N;
    while (lo < hi) { int m = (lo + hi) >> 1; if (batch[m] < g) lo = m + 1; else hi = m; }
    int s = lo;
    hi = N;
    while (lo < hi) { int m = (lo + hi) >> 1; if (batch[m] < g + 1) lo = m + 1; else hi = m; }
    int e = lo;
    int len = e - s;
    int parts = (int)gridDim.y;
    int chunk = (len + parts - 1) / parts;
    int i0 = s + p * chunk;
    int i1 = min(i0 + chunk, e);
    float a0 = 0.f, a1 = 0.f;
    for (int i = i0 + rg; i < i1; i += 4) {
        unsigned int v = H32[(size_t)i * 64 + lane];
        a0 += b2f((unsigned short)(v & 0xffffu));
        a1 += b2f((unsigned short)(v >> 16));
    }
    __shared__ float ps[4][DH];
    ps[rg][lane * 2] = a0;
    ps[rg][lane * 2 + 1] = a1;
    __syncthreads();
    if (t < DH) {
        float v = ps[0][t] + ps[1][t] + ps[2][t] + ps[3][t];
        atomicAdd(&Gsum[g * DH + t], v);
    }
    if (p == 0 && t == 0) cnts[g] = len;
}

// ---------- MLP head + log_softmax (un-permutes Gsum on load) ----------
__global__ __launch_bounds__(64) void k_head(const float* __restrict__ Gsum,
                                             const int* __restrict__ cnts,
                                             const float* __restrict__ W1,
                                             const float* __restrict__ b1,
                                             const float* __restrict__ W2,
                                             const float* __restrict__ b2,
                                             float* __restrict__ out) {
    int g = blockIdx.x;
    int t = threadIdx.x;
    __shared__ float gv[DH];
    __shared__ float mid[20];
    __shared__ float o[10];
    float inv = 1.f / fmaxf((float)cnts[g], 1.f);
    for (int i = t; i < DH; i += 64) {
        int c = ((i & 7) << 4) | (i >> 3);   // true col of permuted pos i
        gv[c] = Gsum[g * DH + i] * inv;
    }
    __syncthreads();
    if (t < 20) {
        float a = b1[t];
        for (int k = 0; k < DH; k++) a += gv[k] * W1[k * 20 + t];
        mid[t] = fmaxf(a, 0.f);
    }
    __syncthreads();
    if (t < 10) {
        float a = b2[t];
        for (int k = 0; k < 20; k++) a += mid[k] * W2[k * 10 + t];
        o[t] = a;
    }
    __syncthreads();
    if (t == 0) {
        float m = -1e30f;
        for (int j = 0; j < 10; j++) m = fmaxf(m, o[j]);
        float ssum = 0.f;
        for (int j = 0; j < 10; j++) ssum += expf(o[j] - m);
        float l = logf(ssum);
        for (int j = 0; j < 10; j++) out[g * 10 + j] = o[j] - m - l;
    }
}

extern "C" void kernel_launch(void* const* d_in, const int* in_sizes, int n_in,
                              void* d_out, int out_size, void* d_ws, size_t ws_size,
                              hipStream_t stream) {
    const float* x    = (const float*)d_in[0];
    const int*   ei   = (const int*)d_in[1];
    const int*   batch= (const int*)d_in[2];
    const float* W1   = (const float*)d_in[3];
    const float* b1   = (const float*)d_in[4];
    const float* W2   = (const float*)d_in[5];
    const float* b2   = (const float*)d_in[6];
    const float* fc1W = (const float*)d_in[7];
    const float* fc1b = (const float*)d_in[8];
    const float* fc2W = (const float*)d_in[9];
    const float* fc2b = (const float*)d_in[10];
    float* out = (float*)d_out;

    int N = in_sizes[0] / DH;     // 100000
    int E = in_sizes[1] / 2;      // 1600000
    int G = out_size / 10;        // 64
    int nbuck = (N + 255) >> 8;   // 391

    char* p = (char*)d_ws;
    auto alloc = [&](size_t bytes) {
        char* r = p;
        p += (bytes + 255) & ~(size_t)255;
        return r;
    };
    // t8 no longer aliases pairs (ws is 256MB, we use ~66MB) -> W-prep is fully
    // independent and rides along in the k_bucket launch.
    unsigned int*   pairs = (unsigned int*)alloc((size_t)nbuck * BCAP * 4);
    unsigned char*  t8    = (unsigned char*)alloc((size_t)(N + 1) * DH); // +1: zero row
    unsigned short* a1 = (unsigned short*)alloc((size_t)N * DH * 2); // bf16 act (both layers)
    int*   csr  = (int*)alloc((size_t)nbuck * BCAP * 4);             // bucket-strided, padded
    int*   off  = (int*)alloc((size_t)N * 4);
    int*   dpd  = (int*)alloc((size_t)N * 4);
    float* dinv = (float*)alloc((size_t)N * 4);
    unsigned short* Wt1 = (unsigned short*)alloc(DH * DH * 2);
    unsigned short* Wt2 = (unsigned short*)alloc(DH * DH * 2);
    float* Gsum = (float*)alloc((size_t)G * DH * 4);
    int*   bcur = (int*)alloc(512 * 16 * 4);
    int*   cnts = (int*)alloc((size_t)G * 4);

    const int* row = ei;       // message source
    const int* col = ei + E;   // aggregation target

    (void)hipMemsetAsync(Gsum, 0, (size_t)G * DH * 4 + 512 * 16 * 4, stream);

    const int chunk = 2048;
    int ablocks = (E + chunk - 1) / chunk;  // 782
    k_bucket<<<ablocks + 128, 256, 0, stream>>>(row, col, E, nbuck, chunk, ablocks,
                                                pairs, bcur, W1, W2, Wt1, Wt2,
                                                (unsigned int*)(t8 + (size_t)N * DH));
    k_build<<<nbuck, 512, 0, stream>>>(pairs, bcur, nbuck, N, off, dpd, dinv, csr);

    int gblocks = (N + 63) / 64;
    int mblocks = (N + 15) / 16;  // 6250
    // layer 1
    k_gemm_mfma<<<gblocks, 256, 0, stream>>>(x, 0, Wt1, dinv, t8, N);
    k_agg<<<mblocks, 256, 0, stream>>>(t8, a1, dinv, off, dpd, csr, b1, 1, N);
    // layer 2
    k_gemm_mfma<<<gblocks, 256, 0, stream>>>(a1, 1, Wt2, dinv, t8, N);
    k_agg<<<mblocks, 256, 0, stream>>>(t8, a1, dinv, off, dpd, csr, b2, 0, N);

    dim3 pg(G, 32);
    k_pool<<<pg, 256, 0, stream>>>((const unsigned int*)a1, batch, Gsum, cnts, N);
    k_head<<<G, 64, 0, stream>>>(Gsum, cnts, fc1W, fc1b, fc2W, fc2b, out);
}

// Round 11
// 284.920 us; speedup vs baseline: 1.0397x; 1.0397x over previous
//
#include <hip/hip_runtime.h>
#include <math.h>

#define DH 128
#define BCAP 16384  // slots per 512-node bucket: edges+self (~8675 mean) + pad fits (20 sigma)

typedef __bf16 bf8_t __attribute__((ext_vector_type(8)));
typedef short short8 __attribute__((ext_vector_type(8)));
typedef float f4_t __attribute__((ext_vector_type(4)));
typedef float f2_t __attribute__((ext_vector_type(2)));

__device__ inline unsigned short f2b(float f) {
    unsigned int u = __builtin_bit_cast(unsigned int, f);
    u = u + 0x7fffu + ((u >> 16) & 1u);  // RNE
    return (unsigned short)(u >> 16);
}
__device__ inline float b2f(unsigned short h) {
    return __builtin_bit_cast(float, (unsigned int)h << 16);
}

// ---------- Pass A: bucket edges by dst>>9 (782 blocks) + fused W-prep blocks ----------
// Blocks [0, ablocks): bucket a chunk of 2048 edges into 512-node buckets.
//   Write phase is LDS counting-sorted: consecutive lanes write consecutive
//   slots of the same bucket (dense coalesced stores; r10 showed the unsorted
//   form runs at 5x write amplification / 64 scattered stores per wave).
// Blocks [ablocks, ablocks+128): W prep (independent; saves one launch):
//   Wt1[n][k] = bf16(W1[k][n]); Wt2[n][p(k)] = bf16(W2[k][n]), p(k)=((k&15)<<3)|(k>>4)
//   (layer-2 k-order permuted to match k_agg's permuted activation bytes);
//   plus zeroing the fp8 table's sentinel row.
__global__ __launch_bounds__(256) void k_bucket(const int* __restrict__ row,
                                                const int* __restrict__ col,
                                                int E, int nbuck, int chunk, int ablocks,
                                                unsigned int* __restrict__ pairs,
                                                int* __restrict__ bcur,
                                                const float* __restrict__ W1,
                                                const float* __restrict__ W2,
                                                unsigned short* __restrict__ Wt1,
                                                unsigned short* __restrict__ Wt2,
                                                unsigned int* __restrict__ t8zrow) {
    int t = threadIdx.x;
    if ((int)blockIdx.x >= ablocks) {
        int bid2 = (int)blockIdx.x - ablocks;
        int g = bid2 * 256 + t;               // 0..32767
        if (bid2 == 0 && t < 32) t8zrow[t] = 0u;
        int v = g & 16383;
        int k = v >> 7, n = v & 127;
        if (g < 16384) {
            Wt1[n * DH + k] = f2b(W1[k * DH + n]);
        } else {
            int p = ((k & 15) << 3) | (k >> 4);
            Wt2[n * DH + p] = f2b(W2[k * DH + n]);
        }
        return;
    }
    __shared__ int lcnt[256];
    __shared__ int lbase[256];
    __shared__ int scn[256];
    __shared__ int lofs[256];
    __shared__ unsigned int srec[2048];
    __shared__ unsigned int srt_val[2048];
    __shared__ unsigned int srt_dst[2048];
    int e0 = blockIdx.x * chunk;
    int e1 = min(e0 + chunk, E);
    lcnt[t] = 0;
    __syncthreads();
    for (int i = e0 + t; i < e1; i += 256) {
        int d = col[i];
        int b = d >> 9;
        int slot = atomicAdd(&lcnt[b], 1);
        srec[i - e0] = ((unsigned int)b << 22) | ((unsigned int)(d & 511) << 13)
                     | (unsigned int)slot;
    }
    __syncthreads();
    {   // global base per bucket + exclusive block-local scan of lcnt
        int c = (t < nbuck) ? lcnt[t] : 0;
        lbase[t] = (c > 0) ? atomicAdd(&bcur[t * 16], c) : 0;  // stride 16: 1 line/counter
        scn[t] = c;
    }
    __syncthreads();
    for (int d = 1; d < 256; d <<= 1) {
        int v = (t >= d) ? scn[t - d] : 0;
        __syncthreads();
        scn[t] += v;
        __syncthreads();
    }
    lofs[t] = scn[t] - ((t < nbuck) ? lcnt[t] : 0);  // exclusive prefix
    __syncthreads();
    for (int i = e0 + t; i < e1; i += 256) {   // place in bucket-sorted order
        unsigned int r = srec[i - e0];
        int b = r >> 22;
        unsigned int dl = (r >> 13) & 511u;
        int slot = (int)(r & 8191u);
        int p = lofs[b] + slot;
        int g = lbase[b] + slot;
        srt_val[p] = ((unsigned int)row[i] << 9) | dl;
        srt_dst[p] = (g < BCAP) ? (unsigned int)(b * BCAP + g) : 0xFFFFFFFFu;
    }
    __syncthreads();
    int cnt = e1 - e0;
    for (int i = t; i < cnt; i += 256) {       // coalesced: consecutive lanes ->
        unsigned int d = srt_dst[i];           // consecutive slots, same bucket
        if (d != 0xFFFFFFFFu) pairs[d] = srt_val[i];
    }
}

// ---------- Pass B: per-bucket build, 512 threads (one node/thread), monolithic ----------
// Bucket-local scatter (one block owns one csr region -> one L2, no cross-XCD
// write amplification -- r7 lesson). Runs = [self, edges..., sentinels...]
// padded to x16 with sentinel index N (zero table row). dinv = rsqrt(deg+1).
__global__ __launch_bounds__(512) void k_build(const unsigned int* __restrict__ pairs,
                                               const int* __restrict__ bcur,
                                               int nbuck, int N,
                                               int* __restrict__ off,
                                               int* __restrict__ dpd,
                                               float* __restrict__ dinv,
                                               int* __restrict__ csr) {
    __shared__ int cnt2[512];
    __shared__ int scn[512];
    __shared__ int curi[512];
    int b = blockIdx.x, t = threadIdx.x;
    int cnt = min(bcur[b * 16], BCAP);
    int base = b * BCAP;           // bucket-strided csr region
    int node0 = b << 9;
    int nodes = min(512, N - node0);
    cnt2[t] = (t < nodes) ? 1 : 0;            // seed self edge
    __syncthreads();
    const unsigned int* pp = pairs + (size_t)b * BCAP;
    for (int i = t; i < cnt; i += 512)
        atomicAdd(&cnt2[pp[i] & 511u], 1);
    __syncthreads();
    int c = cnt2[t];                          // 1 + indegree (0 for t>=nodes)
    int pdv = (c + 15) & ~15;
    scn[t] = pdv;
    __syncthreads();
    for (int d = 1; d < 512; d <<= 1) {       // Hillis-Steele inclusive scan
        int v = (t >= d) ? scn[t - d] : 0;
        __syncthreads();
        scn[t] += v;
        __syncthreads();
    }
    int exc = min(scn[t] - pdv, BCAP);        // exclusive prefix (mult of 16)
    int avail = BCAP - exc;
    int pdc = min(pdv, avail);                // monotone clamp (~never fires, 20 sigma)
    curi[t] = exc + 1;                        // scatter starts after self edge
    if (t < nodes) {
        off[node0 + t] = base + exc;
        dpd[node0 + t] = pdc;
        dinv[node0 + t] = rsqrtf((float)c);
        if (pdc > 0) csr[base + exc] = node0 + t;                 // self edge
        for (int k = c; k < pdc; k++) csr[base + exc + k] = N;    // sentinels
    }
    __syncthreads();
    for (int i = t; i < cnt; i += 512) {
        unsigned int p = pp[i];
        int d = (int)(p & 511u);
        int slot = atomicAdd(&curi[d], 1);
        if (slot < BCAP) csr[base + slot] = (int)(p >> 9);
    }
}

// ---------- MFMA GEMM -> fp8 e4m3 table, lane-major permuted rows ----------
__global__ __launch_bounds__(256) void k_gemm_mfma(const void* __restrict__ Xin, int x_is_bf16,
                                                   const unsigned short* __restrict__ Wt,
                                                   const float* __restrict__ dinv,
                                                   unsigned char* __restrict__ Y, int nrows) {
    __shared__ unsigned short Xs[64 * 136];
    __shared__ unsigned short Ws[128 * 136];
    int t = threadIdx.x;
    int row0 = blockIdx.x * 64;

    for (int v = t; v < 128 * 32; v += 256) {
        int n = v >> 5, kq = v & 31;
        ushort4 w = ((const ushort4*)Wt)[v];
        *(ushort4*)&Ws[n * 136 + kq * 4] = w;
    }
    if (x_is_bf16) {
        const unsigned short* X = (const unsigned short*)Xin;
        for (int v = t; v < 64 * 32; v += 256) {
            int r = v >> 5, cq = v & 31;
            int gr = row0 + r;
            ushort4 h;
            if (gr < nrows) h = ((const ushort4*)X)[(size_t)gr * 32 + cq];
            else { h.x = 0; h.y = 0; h.z = 0; h.w = 0; }
            *(ushort4*)&Xs[r * 136 + cq * 4] = h;
        }
    } else {
        const float* X = (const float*)Xin;
        for (int v = t; v < 64 * 32; v += 256) {
            int r = v >> 5, cq = v & 31;
            int gr = row0 + r;
            ushort4 h;
            if (gr < nrows) {
                float4 xv = ((const float4*)X)[(size_t)gr * 32 + cq];
                h.x = f2b(xv.x); h.y = f2b(xv.y); h.z = f2b(xv.z); h.w = f2b(xv.w);
            } else { h.x = 0; h.y = 0; h.z = 0; h.w = 0; }
            *(ushort4*)&Xs[r * 136 + cq * 4] = h;
        }
    }
    __syncthreads();

    int w = t >> 6;
    int lane = t & 63;
    int quad = lane >> 4;
    int l16 = lane & 15;
    int rw = w * 16;

    f4_t acc[8];
#pragma unroll
    for (int j = 0; j < 8; j++) acc[j] = (f4_t){0.f, 0.f, 0.f, 0.f};

#pragma unroll
    for (int kk = 0; kk < 4; kk++) {
        int k0 = kk * 32;
        bf8_t a = __builtin_bit_cast(bf8_t,
            *(const short8*)&Xs[(rw + l16) * 136 + k0 + quad * 8]);
#pragma unroll
        for (int j = 0; j < 8; j++) {
            bf8_t b = __builtin_bit_cast(bf8_t,
                *(const short8*)&Ws[(j * 16 + l16) * 136 + k0 + quad * 8]);
            acc[j] = __builtin_amdgcn_mfma_f32_16x16x32_bf16(a, b, acc[j], 0, 0, 0);
        }
    }

#pragma unroll
    for (int reg = 0; reg < 4; reg++) {
        int r = row0 + rw + quad * 4 + reg;
        if (r < nrows) {
            float dv = dinv[r];
            float v0 = acc[0][reg] * dv, v1 = acc[1][reg] * dv;
            float v2 = acc[2][reg] * dv, v3 = acc[3][reg] * dv;
            float v4 = acc[4][reg] * dv, v5 = acc[5][reg] * dv;
            float v6 = acc[6][reg] * dv, v7 = acc[7][reg] * dv;
            int d0 = __builtin_amdgcn_cvt_pk_fp8_f32(v0, v1, 0, false);
            d0 = __builtin_amdgcn_cvt_pk_fp8_f32(v2, v3, d0, true);
            int d1 = __builtin_amdgcn_cvt_pk_fp8_f32(v4, v5, 0, false);
            d1 = __builtin_amdgcn_cvt_pk_fp8_f32(v6, v7, d1, true);
            *(uint2*)&Y[(size_t)r * DH + l16 * 8] = make_uint2((unsigned)d0, (unsigned)d1);
        }
    }
}

// ---------- Gather core: 8-deep unmasked round ----------
#define AGG_ROUND(IDX)                                                     \
    {                                                                      \
        int ea = be + i;                                                   \
        unsigned v0 = ((unsigned)IDX(ea)     << 7) | l5b;                  \
        unsigned v1 = ((unsigned)IDX(ea + 1) << 7) | l5b;                  \
        unsigned v2 = ((unsigned)IDX(ea + 2) << 7) | l5b;                  \
        unsigned v3 = ((unsigned)IDX(ea + 3) << 7) | l5b;                  \
        unsigned v4 = ((unsigned)IDX(ea + 4) << 7) | l5b;                  \
        unsigned v5 = ((unsigned)IDX(ea + 5) << 7) | l5b;                  \
        unsigned v6 = ((unsigned)IDX(ea + 6) << 7) | l5b;                  \
        unsigned v7 = ((unsigned)IDX(ea + 7) << 7) | l5b;                  \
        unsigned int u0 = *(const unsigned int*)(Tb + v0);                 \
        unsigned int u1 = *(const unsigned int*)(Tb + v1);                 \
        unsigned int u2 = *(const unsigned int*)(Tb + v2);                 \
        unsigned int u3 = *(const unsigned int*)(Tb + v3);                 \
        unsigned int u4 = *(const unsigned int*)(Tb + v4);                 \
        unsigned int u5 = *(const unsigned int*)(Tb + v5);                 \
        unsigned int u6 = *(const unsigned int*)(Tb + v6);                 \
        unsigned int u7 = *(const unsigned int*)(Tb + v7);                 \
        accA01 += __builtin_amdgcn_cvt_pk_f32_fp8(u0, false);              \
        accA23 += __builtin_amdgcn_cvt_pk_f32_fp8(u0, true);               \
        accB01 += __builtin_amdgcn_cvt_pk_f32_fp8(u1, false);              \
        accB23 += __builtin_amdgcn_cvt_pk_f32_fp8(u1, true);               \
        accA01 += __builtin_amdgcn_cvt_pk_f32_fp8(u2, false);              \
        accA23 += __builtin_amdgcn_cvt_pk_f32_fp8(u2, true);               \
        accB01 += __builtin_amdgcn_cvt_pk_f32_fp8(u3, false);              \
        accB23 += __builtin_amdgcn_cvt_pk_f32_fp8(u3, true);               \
        accA01 += __builtin_amdgcn_cvt_pk_f32_fp8(u4, false);              \
        accA23 += __builtin_amdgcn_cvt_pk_f32_fp8(u4, true);               \
        accB01 += __builtin_amdgcn_cvt_pk_f32_fp8(u5, false);              \
        accB23 += __builtin_amdgcn_cvt_pk_f32_fp8(u5, true);               \
        accA01 += __builtin_amdgcn_cvt_pk_f32_fp8(u6, false);              \
        accA23 += __builtin_amdgcn_cvt_pk_f32_fp8(u6, true);               \
        accB01 += __builtin_amdgcn_cvt_pk_f32_fp8(u7, false);              \
        accB23 += __builtin_amdgcn_cvt_pk_f32_fp8(u7, true);               \
    }

// ---------- Gather-accumulate aggregation (round-5 proven form, unchanged) ----------
__global__ __launch_bounds__(256) void k_agg(const unsigned char* __restrict__ T,
                                             unsigned short* __restrict__ Out,
                                             const float* __restrict__ dinv,
                                             const int* __restrict__ off,
                                             const int* __restrict__ dpd,
                                             const int* __restrict__ csr,
                                             const float* __restrict__ bias,
                                             int elu, int N) {
    __shared__ int ofs[16];
    __shared__ int pds[16];
    __shared__ float dv16[16];
    __shared__ int sidx[768];
    int t = threadIdx.x;
    int d0 = blockIdx.x * 16;
    if (t < 16) {
        int n = min(d0 + t, N - 1);
        ofs[t] = off[n];
        pds[t] = dpd[n];
        dv16[t] = dinv[n];
    }
    __syncthreads();
    int s0 = ofs[0];
    int span = ofs[15] + pds[15] - s0;  // contiguous: 16 | 512, same bucket
    int scnt = min(span, 768);
    for (int k = t; k < scnt; k += 256) sidx[k] = csr[s0 + k];
    __syncthreads();

    int w = t >> 6;
    int lane = t & 63;
    int half = lane >> 5;
    int l5 = lane & 31;
    unsigned l5b = (unsigned)(l5 << 2);
    const char* Tb = (const char*)T;

    // permuted slot p = 4*l5+b holds true col 64*(l5&1) + 16*b + (l5>>1)
    int c0 = ((l5 & 1) << 6) | (l5 >> 1);
    float bb0 = bias[c0], bb1 = bias[c0 + 16], bb2 = bias[c0 + 32], bb3 = bias[c0 + 48];

    for (int ni = 0; ni < 4; ni++) {
        int nl = 4 * w + ni;
        int nd = d0 + nl;
        if (nd >= N) break;
        int eL = ofs[nl] - s0;
        int pd = pds[nl];
        int K = pd >> 1;           // per-half run; multiple of 8
        int be = eL + half * K;    // contiguous half

        f2_t accA01 = (f2_t){0.f, 0.f}, accA23 = (f2_t){0.f, 0.f};
        f2_t accB01 = (f2_t){0.f, 0.f}, accB23 = (f2_t){0.f, 0.f};

        if (eL + pd <= scnt) {
#define IDX_L(e) sidx[e]
            for (int i = 0; i < K; i += 8) AGG_ROUND(IDX_L)
#undef IDX_L
        } else {
            const int* gp = csr + s0;   // rare: slice > 768 (staging overflow)
#define IDX_G(e) gp[e]
            for (int i = 0; i < K; i += 8) AGG_ROUND(IDX_G)
#undef IDX_G
        }

        float a0 = accA01[0] + accB01[0];
        float a1 = accA01[1] + accB01[1];
        float a2 = accA23[0] + accB23[0];
        float a3 = accA23[1] + accB23[1];
        a0 += __shfl_xor(a0, 32);
        a1 += __shfl_xor(a1, 32);
        a2 += __shfl_xor(a2, 32);
        a3 += __shfl_xor(a3, 32);

        if (!half) {
            float dv = dv16[nl];
            float o0 = a0 * dv + bb0;
            float o1 = a1 * dv + bb1;
            float o2 = a2 * dv + bb2;
            float o3 = a3 * dv + bb3;
            if (elu) {
                o0 = o0 > 0.f ? o0 : __expf(o0) - 1.f;
                o1 = o1 > 0.f ? o1 : __expf(o1) - 1.f;
                o2 = o2 > 0.f ? o2 : __expf(o2) - 1.f;
                o3 = o3 > 0.f ? o3 : __expf(o3) - 1.f;
            }
            unsigned int p0 = (unsigned int)f2b(o0) | ((unsigned int)f2b(o1) << 16);
            unsigned int p1 = (unsigned int)f2b(o2) | ((unsigned int)f2b(o3) << 16);
            *(uint2*)&Out[(size_t)nd * DH + (l5 << 2)] = make_uint2(p0, p1);
        }
    }
}

// ---------- Mean pool: wave-per-row streaming, (G x 32) blocks, bf16 input ----------
// Input rows are in permuted byte order; Gsum stays permuted (k_head fixes).
__global__ __launch_bounds__(256) void k_pool(const unsigned int* __restrict__ H32,
                                              const int* __restrict__ batch,
                                              float* __restrict__ Gsum,
                                              int* __restrict__ cnts, int N) {
    int g = blockIdx.x;
    int p = blockIdx.y;
    int t = threadIdx.x;
    int lane = t & 63;
    int rg = t >> 6;  // wave 0..3
    int lo = 0, hi = N;
    while (lo < hi) { int m = (lo + hi) >> 1; if (batch[m] < g) lo = m + 1; else hi = m; }
    int s = lo;
    hi = N;
    while (lo < hi) { int m = (lo + hi) >> 1; if (batch[m] < g + 1) lo = m + 1; else hi = m; }
    int e = lo;
    int len = e - s;
    int parts = (int)gridDim.y;
    int chunk = (len + parts - 1) / parts;
    int i0 = s + p * chunk;
    int i1 = min(i0 + chunk, e);
    float a0 = 0.f, a1 = 0.f;
    for (int i = i0 + rg; i < i1; i += 4) {
        unsigned int v = H32[(size_t)i * 64 + lane];
        a0 += b2f((unsigned short)(v & 0xffffu));
        a1 += b2f((unsigned short)(v >> 16));
    }
    __shared__ float ps[4][DH];
    ps[rg][lane * 2] = a0;
    ps[rg][lane * 2 + 1] = a1;
    __syncthreads();
    if (t < DH) {
        float v = ps[0][t] + ps[1][t] + ps[2][t] + ps[3][t];
        atomicAdd(&Gsum[g * DH + t], v);
    }
    if (p == 0 && t == 0) cnts[g] = len;
}

// ---------- MLP head + log_softmax (un-permutes Gsum on load) ----------
__global__ __launch_bounds__(64) void k_head(const float* __restrict__ Gsum,
                                             const int* __restrict__ cnts,
                                             const float* __restrict__ W1,
                                             const float* __restrict__ b1,
                                             const float* __restrict__ W2,
                                             const float* __restrict__ b2,
                                             float* __restrict__ out) {
    int g = blockIdx.x;
    int t = threadIdx.x;
    __shared__ float gv[DH];
    __shared__ float mid[20];
    __shared__ float o[10];
    float inv = 1.f / fmaxf((float)cnts[g], 1.f);
    for (int i = t; i < DH; i += 64) {
        int c = ((i & 7) << 4) | (i >> 3);   // true col of permuted pos i
        gv[c] = Gsum[g * DH + i] * inv;
    }
    __syncthreads();
    if (t < 20) {
        float a = b1[t];
        for (int k = 0; k < DH; k++) a += gv[k] * W1[k * 20 + t];
        mid[t] = fmaxf(a, 0.f);
    }
    __syncthreads();
    if (t < 10) {
        float a = b2[t];
        for (int k = 0; k < 20; k++) a += mid[k] * W2[k * 10 + t];
        o[t] = a;
    }
    __syncthreads();
    if (t == 0) {
        float m = -1e30f;
        for (int j = 0; j < 10; j++) m = fmaxf(m, o[j]);
        float ssum = 0.f;
        for (int j = 0; j < 10; j++) ssum += expf(o[j] - m);
        float l = logf(ssum);
        for (int j = 0; j < 10; j++) out[g * 10 + j] = o[j] - m - l;
    }
}

extern "C" void kernel_launch(void* const* d_in, const int* in_sizes, int n_in,
                              void* d_out, int out_size, void* d_ws, size_t ws_size,
                              hipStream_t stream) {
    const float* x    = (const float*)d_in[0];
    const int*   ei   = (const int*)d_in[1];
    const int*   batch= (const int*)d_in[2];
    const float* W1   = (const float*)d_in[3];
    const float* b1   = (const float*)d_in[4];
    const float* W2   = (const float*)d_in[5];
    const float* b2   = (const float*)d_in[6];
    const float* fc1W = (const float*)d_in[7];
    const float* fc1b = (const float*)d_in[8];
    const float* fc2W = (const float*)d_in[9];
    const float* fc2b = (const float*)d_in[10];
    float* out = (float*)d_out;

    int N = in_sizes[0] / DH;     // 100000
    int E = in_sizes[1] / 2;      // 1600000
    int G = out_size / 10;        // 64
    int nbuck = (N + 511) >> 9;   // 196

    char* p = (char*)d_ws;
    auto alloc = [&](size_t bytes) {
        char* r = p;
        p += (bytes + 255) & ~(size_t)255;
        return r;
    };
    // t8 not aliased with pairs (ws 256MB, we use ~80MB) -> W-prep is fully
    // independent and rides along in the k_bucket launch.
    unsigned int*   pairs = (unsigned int*)alloc((size_t)nbuck * BCAP * 4);
    unsigned char*  t8    = (unsigned char*)alloc((size_t)(N + 1) * DH); // +1: zero row
    unsigned short* a1 = (unsigned short*)alloc((size_t)N * DH * 2); // bf16 act (both layers)
    int*   csr  = (int*)alloc((size_t)nbuck * BCAP * 4);             // bucket-strided, padded
    int*   off  = (int*)alloc((size_t)N * 4);
    int*   dpd  = (int*)alloc((size_t)N * 4);
    float* dinv = (float*)alloc((size_t)N * 4);
    unsigned short* Wt1 = (unsigned short*)alloc(DH * DH * 2);
    unsigned short* Wt2 = (unsigned short*)alloc(DH * DH * 2);
    float* Gsum = (float*)alloc((size_t)G * DH * 4);
    int*   bcur = (int*)alloc(256 * 16 * 4);
    int*   cnts = (int*)alloc((size_t)G * 4);

    const int* row = ei;       // message source
    const int* col = ei + E;   // aggregation target

    (void)hipMemsetAsync(Gsum, 0, (size_t)G * DH * 4 + 256 * 16 * 4, stream);

    const int chunk = 2048;
    int ablocks = (E + chunk - 1) / chunk;  // 782
    k_bucket<<<ablocks + 128, 256, 0, stream>>>(row, col, E, nbuck, chunk, ablocks,
                                                pairs, bcur, W1, W2, Wt1, Wt2,
                                                (unsigned int*)(t8 + (size_t)N * DH));
    k_build<<<nbuck, 512, 0, stream>>>(pairs, bcur, nbuck, N, off, dpd, dinv, csr);

    int gblocks = (N + 63) / 64;
    int mblocks = (N + 15) / 16;  // 6250
    // layer 1
    k_gemm_mfma<<<gblocks, 256, 0, stream>>>(x, 0, Wt1, dinv, t8, N);
    k_agg<<<mblocks, 256, 0, stream>>>(t8, a1, dinv, off, dpd, csr, b1, 1, N);
    // layer 2
    k_gemm_mfma<<<gblocks, 256, 0, stream>>>(a1, 1, Wt2, dinv, t8, N);
    k_agg<<<mblocks, 256, 0, stream>>>(t8, a1, dinv, off, dpd, csr, b2, 0, N);

    dim3 pg(G, 32);
    k_pool<<<pg, 256, 0, stream>>>((const unsigned int*)a1, batch, Gsum, cnts, N);
    k_head<<<G, 64, 0, stream>>>(Gsum, cnts, fc1W, fc1b, fc2W, fc2b, out);
}

// Round 12
// 276.241 us; speedup vs baseline: 1.0724x; 1.0314x over previous
//
#include <hip/hip_runtime.h>
#include <math.h>

#define DH 128
#define BCAP 16384  // slots per 512-node bucket: edges+self (~8675 mean) + pad fits (20 sigma)

typedef __bf16 bf8_t __attribute__((ext_vector_type(8)));
typedef short short8 __attribute__((ext_vector_type(8)));
typedef float f4_t __attribute__((ext_vector_type(4)));
typedef float f2_t __attribute__((ext_vector_type(2)));

__device__ inline unsigned short f2b(float f) {
    unsigned int u = __builtin_bit_cast(unsigned int, f);
    u = u + 0x7fffu + ((u >> 16) & 1u);  // RNE
    return (unsigned short)(u >> 16);
}
__device__ inline float b2f(unsigned short h) {
    return __builtin_bit_cast(float, (unsigned int)h << 16);
}

// ---------- Pass A: bucket edges by dst>>9 (782 blocks) + fused W-prep blocks ----------
// Blocks [0, ablocks): bucket a chunk of 2048 edges into 512-node buckets.
//   Write phase is LDS counting-sorted: consecutive lanes write consecutive
//   slots of the same bucket (dense coalesced stores; r10 showed the unsorted
//   form runs at 5x write amplification / 64 scattered stores per wave).
// Blocks [ablocks, ablocks+128): W prep (independent; saves one launch).
__global__ __launch_bounds__(256) void k_bucket(const int* __restrict__ row,
                                                const int* __restrict__ col,
                                                int E, int nbuck, int chunk, int ablocks,
                                                unsigned int* __restrict__ pairs,
                                                int* __restrict__ bcur,
                                                const float* __restrict__ W1,
                                                const float* __restrict__ W2,
                                                unsigned short* __restrict__ Wt1,
                                                unsigned short* __restrict__ Wt2,
                                                unsigned int* __restrict__ t8zrow) {
    int t = threadIdx.x;
    if ((int)blockIdx.x >= ablocks) {
        int bid2 = (int)blockIdx.x - ablocks;
        int g = bid2 * 256 + t;               // 0..32767
        if (bid2 == 0 && t < 32) t8zrow[t] = 0u;
        int v = g & 16383;
        int k = v >> 7, n = v & 127;
        if (g < 16384) {
            Wt1[n * DH + k] = f2b(W1[k * DH + n]);
        } else {
            int p = ((k & 15) << 3) | (k >> 4);
            Wt2[n * DH + p] = f2b(W2[k * DH + n]);
        }
        return;
    }
    __shared__ int lcnt[256];
    __shared__ int lbase[256];
    __shared__ int scn[256];
    __shared__ int lofs[256];
    __shared__ unsigned int srec[2048];
    __shared__ unsigned int srt_val[2048];
    __shared__ unsigned int srt_dst[2048];
    int e0 = blockIdx.x * chunk;
    int e1 = min(e0 + chunk, E);
    lcnt[t] = 0;
    __syncthreads();
    for (int i = e0 + t; i < e1; i += 256) {
        int d = col[i];
        int b = d >> 9;
        int slot = atomicAdd(&lcnt[b], 1);
        srec[i - e0] = ((unsigned int)b << 22) | ((unsigned int)(d & 511) << 13)
                     | (unsigned int)slot;
    }
    __syncthreads();
    {   // global base per bucket + exclusive block-local scan of lcnt
        int c = (t < nbuck) ? lcnt[t] : 0;
        lbase[t] = (c > 0) ? atomicAdd(&bcur[t * 16], c) : 0;  // stride 16: 1 line/counter
        scn[t] = c;
    }
    __syncthreads();
    for (int d = 1; d < 256; d <<= 1) {
        int v = (t >= d) ? scn[t - d] : 0;
        __syncthreads();
        scn[t] += v;
        __syncthreads();
    }
    lofs[t] = scn[t] - ((t < nbuck) ? lcnt[t] : 0);  // exclusive prefix
    __syncthreads();
    for (int i = e0 + t; i < e1; i += 256) {   // place in bucket-sorted order
        unsigned int r = srec[i - e0];
        int b = r >> 22;
        unsigned int dl = (r >> 13) & 511u;
        int slot = (int)(r & 8191u);
        int p = lofs[b] + slot;
        int g = lbase[b] + slot;
        srt_val[p] = ((unsigned int)row[i] << 9) | dl;
        srt_dst[p] = (g < BCAP) ? (unsigned int)(b * BCAP + g) : 0xFFFFFFFFu;
    }
    __syncthreads();
    int cnt = e1 - e0;
    for (int i = t; i < cnt; i += 256) {       // coalesced: consecutive lanes ->
        unsigned int d = srt_dst[i];           // consecutive slots, same bucket
        if (d != 0xFFFFFFFFu) pairs[d] = srt_val[i];
    }
}

// ---------- Pass B: per-bucket build, 512 threads; LDS csr image + coalesced dump ----
// Count -> scan -> scatter into a 64KB LDS image of the bucket's csr region
// (self edge + real edges + sentinels, all LDS writes), then ONE coalesced
// stride-512 dump to global (runs are contiguous, exc multiples of 16 dwords).
// r12: removes ~12K scattered 4B global writes per block (same disease/cure
// as k_bucket's r11 counting sort). Bucket-local (r7 lesson) preserved.
__global__ __launch_bounds__(512) void k_build(const unsigned int* __restrict__ pairs,
                                               const int* __restrict__ bcur,
                                               int nbuck, int N,
                                               int* __restrict__ off,
                                               int* __restrict__ dpd,
                                               float* __restrict__ dinv,
                                               int* __restrict__ csr) {
    __shared__ int cnt2[512];
    __shared__ int scn[512];
    __shared__ int curi[512];
    __shared__ int scsr[BCAP];   // 64KB LDS image of this bucket's csr region
    int b = blockIdx.x, t = threadIdx.x;
    int cnt = min(bcur[b * 16], BCAP);
    int base = b * BCAP;           // bucket-strided csr region
    int node0 = b << 9;
    int nodes = min(512, N - node0);
    cnt2[t] = (t < nodes) ? 1 : 0;            // seed self edge
    __syncthreads();
    const unsigned int* pp = pairs + (size_t)b * BCAP;
    for (int i = t; i < cnt; i += 512)
        atomicAdd(&cnt2[pp[i] & 511u], 1);
    __syncthreads();
    int c = cnt2[t];                          // 1 + indegree (0 for t>=nodes)
    int pdv = (c + 15) & ~15;
    scn[t] = pdv;
    __syncthreads();
    for (int d = 1; d < 512; d <<= 1) {       // Hillis-Steele inclusive scan
        int v = (t >= d) ? scn[t - d] : 0;
        __syncthreads();
        scn[t] += v;
        __syncthreads();
    }
    int exc = min(scn[t] - pdv, BCAP);        // exclusive prefix (mult of 16)
    int avail = BCAP - exc;
    int pdc = min(pdv, avail);                // monotone clamp (~never fires, 20 sigma)
    curi[t] = exc + 1;                        // scatter starts after self edge
    if (t < nodes) {
        off[node0 + t] = base + exc;
        dpd[node0 + t] = pdc;
        dinv[node0 + t] = rsqrtf((float)c);
        if (pdc > 0) scsr[exc] = node0 + t;                       // self edge
        for (int k = c; k < pdc; k++) scsr[exc + k] = N;          // sentinels
    }
    __syncthreads();
    for (int i = t; i < cnt; i += 512) {      // scatter real edges into LDS
        unsigned int p = pp[i];
        int d = (int)(p & 511u);
        int slot = atomicAdd(&curi[d], 1);
        if (slot < BCAP) scsr[slot] = (int)(p >> 9);
    }
    __syncthreads();
    int total = min(scn[511], BCAP);          // full padded span (contiguous runs)
    for (int i = t; i < total; i += 512)      // coalesced dump: lanes -> dwords
        csr[base + i] = scsr[i];
}

// ---------- MFMA GEMM -> fp8 e4m3 table, lane-major permuted rows ----------
__global__ __launch_bounds__(256) void k_gemm_mfma(const void* __restrict__ Xin, int x_is_bf16,
                                                   const unsigned short* __restrict__ Wt,
                                                   const float* __restrict__ dinv,
                                                   unsigned char* __restrict__ Y, int nrows) {
    __shared__ unsigned short Xs[64 * 136];
    __shared__ unsigned short Ws[128 * 136];
    int t = threadIdx.x;
    int row0 = blockIdx.x * 64;

    for (int v = t; v < 128 * 32; v += 256) {
        int n = v >> 5, kq = v & 31;
        ushort4 w = ((const ushort4*)Wt)[v];
        *(ushort4*)&Ws[n * 136 + kq * 4] = w;
    }
    if (x_is_bf16) {
        const unsigned short* X = (const unsigned short*)Xin;
        for (int v = t; v < 64 * 32; v += 256) {
            int r = v >> 5, cq = v & 31;
            int gr = row0 + r;
            ushort4 h;
            if (gr < nrows) h = ((const ushort4*)X)[(size_t)gr * 32 + cq];
            else { h.x = 0; h.y = 0; h.z = 0; h.w = 0; }
            *(ushort4*)&Xs[r * 136 + cq * 4] = h;
        }
    } else {
        const float* X = (const float*)Xin;
        for (int v = t; v < 64 * 32; v += 256) {
            int r = v >> 5, cq = v & 31;
            int gr = row0 + r;
            ushort4 h;
            if (gr < nrows) {
                float4 xv = ((const float4*)X)[(size_t)gr * 32 + cq];
                h.x = f2b(xv.x); h.y = f2b(xv.y); h.z = f2b(xv.z); h.w = f2b(xv.w);
            } else { h.x = 0; h.y = 0; h.z = 0; h.w = 0; }
            *(ushort4*)&Xs[r * 136 + cq * 4] = h;
        }
    }
    __syncthreads();

    int w = t >> 6;
    int lane = t & 63;
    int quad = lane >> 4;
    int l16 = lane & 15;
    int rw = w * 16;

    f4_t acc[8];
#pragma unroll
    for (int j = 0; j < 8; j++) acc[j] = (f4_t){0.f, 0.f, 0.f, 0.f};

#pragma unroll
    for (int kk = 0; kk < 4; kk++) {
        int k0 = kk * 32;
        bf8_t a = __builtin_bit_cast(bf8_t,
            *(const short8*)&Xs[(rw + l16) * 136 + k0 + quad * 8]);
#pragma unroll
        for (int j = 0; j < 8; j++) {
            bf8_t b = __builtin_bit_cast(bf8_t,
                *(const short8*)&Ws[(j * 16 + l16) * 136 + k0 + quad * 8]);
            acc[j] = __builtin_amdgcn_mfma_f32_16x16x32_bf16(a, b, acc[j], 0, 0, 0);
        }
    }

#pragma unroll
    for (int reg = 0; reg < 4; reg++) {
        int r = row0 + rw + quad * 4 + reg;
        if (r < nrows) {
            float dv = dinv[r];
            float v0 = acc[0][reg] * dv, v1 = acc[1][reg] * dv;
            float v2 = acc[2][reg] * dv, v3 = acc[3][reg] * dv;
            float v4 = acc[4][reg] * dv, v5 = acc[5][reg] * dv;
            float v6 = acc[6][reg] * dv, v7 = acc[7][reg] * dv;
            int d0 = __builtin_amdgcn_cvt_pk_fp8_f32(v0, v1, 0, false);
            d0 = __builtin_amdgcn_cvt_pk_fp8_f32(v2, v3, d0, true);
            int d1 = __builtin_amdgcn_cvt_pk_fp8_f32(v4, v5, 0, false);
            d1 = __builtin_amdgcn_cvt_pk_fp8_f32(v6, v7, d1, true);
            *(uint2*)&Y[(size_t)r * DH + l16 * 8] = make_uint2((unsigned)d0, (unsigned)d1);
        }
    }
}

// ---------- Gather core: 8-deep unmasked round ----------
#define AGG_ROUND(IDX)                                                     \
    {                                                                      \
        int ea = be + i;                                                   \
        unsigned v0 = ((unsigned)IDX(ea)     << 7) | l5b;                  \
        unsigned v1 = ((unsigned)IDX(ea + 1) << 7) | l5b;                  \
        unsigned v2 = ((unsigned)IDX(ea + 2) << 7) | l5b;                  \
        unsigned v3 = ((unsigned)IDX(ea + 3) << 7) | l5b;                  \
        unsigned v4 = ((unsigned)IDX(ea + 4) << 7) | l5b;                  \
        unsigned v5 = ((unsigned)IDX(ea + 5) << 7) | l5b;                  \
        unsigned v6 = ((unsigned)IDX(ea + 6) << 7) | l5b;                  \
        unsigned v7 = ((unsigned)IDX(ea + 7) << 7) | l5b;                  \
        unsigned int u0 = *(const unsigned int*)(Tb + v0);                 \
        unsigned int u1 = *(const unsigned int*)(Tb + v1);                 \
        unsigned int u2 = *(const unsigned int*)(Tb + v2);                 \
        unsigned int u3 = *(const unsigned int*)(Tb + v3);                 \
        unsigned int u4 = *(const unsigned int*)(Tb + v4);                 \
        unsigned int u5 = *(const unsigned int*)(Tb + v5);                 \
        unsigned int u6 = *(const unsigned int*)(Tb + v6);                 \
        unsigned int u7 = *(const unsigned int*)(Tb + v7);                 \
        accA01 += __builtin_amdgcn_cvt_pk_f32_fp8(u0, false);              \
        accA23 += __builtin_amdgcn_cvt_pk_f32_fp8(u0, true);               \
        accB01 += __builtin_amdgcn_cvt_pk_f32_fp8(u1, false);              \
        accB23 += __builtin_amdgcn_cvt_pk_f32_fp8(u1, true);               \
        accA01 += __builtin_amdgcn_cvt_pk_f32_fp8(u2, false);              \
        accA23 += __builtin_amdgcn_cvt_pk_f32_fp8(u2, true);               \
        accB01 += __builtin_amdgcn_cvt_pk_f32_fp8(u3, false);              \
        accB23 += __builtin_amdgcn_cvt_pk_f32_fp8(u3, true);               \
        accA01 += __builtin_amdgcn_cvt_pk_f32_fp8(u4, false);              \
        accA23 += __builtin_amdgcn_cvt_pk_f32_fp8(u4, true);               \
        accB01 += __builtin_amdgcn_cvt_pk_f32_fp8(u5, false);              \
        accB23 += __builtin_amdgcn_cvt_pk_f32_fp8(u5, true);               \
        accA01 += __builtin_amdgcn_cvt_pk_f32_fp8(u6, false);              \
        accA23 += __builtin_amdgcn_cvt_pk_f32_fp8(u6, true);               \
        accB01 += __builtin_amdgcn_cvt_pk_f32_fp8(u7, false);              \
        accB23 += __builtin_amdgcn_cvt_pk_f32_fp8(u7, true);               \
    }

// ---------- Gather-accumulate aggregation (round-5 proven form, unchanged) ----------
__global__ __launch_bounds__(256) void k_agg(const unsigned char* __restrict__ T,
                                             unsigned short* __restrict__ Out,
                                             const float* __restrict__ dinv,
                                             const int* __restrict__ off,
                                             const int* __restrict__ dpd,
                                             const int* __restrict__ csr,
                                             const float* __restrict__ bias,
                                             int elu, int N) {
    __shared__ int ofs[16];
    __shared__ int pds[16];
    __shared__ float dv16[16];
    __shared__ int sidx[768];
    int t = threadIdx.x;
    int d0 = blockIdx.x * 16;
    if (t < 16) {
        int n = min(d0 + t, N - 1);
        ofs[t] = off[n];
        pds[t] = dpd[n];
        dv16[t] = dinv[n];
    }
    __syncthreads();
    int s0 = ofs[0];
    int span = ofs[15] + pds[15] - s0;  // contiguous: 16 | 512, same bucket
    int scnt = min(span, 768);
    for (int k = t; k < scnt; k += 256) sidx[k] = csr[s0 + k];
    __syncthreads();

    int w = t >> 6;
    int lane = t & 63;
    int half = lane >> 5;
    int l5 = lane & 31;
    unsigned l5b = (unsigned)(l5 << 2);
    const char* Tb = (const char*)T;

    // permuted slot p = 4*l5+b holds true col 64*(l5&1) + 16*b + (l5>>1)
    int c0 = ((l5 & 1) << 6) | (l5 >> 1);
    float bb0 = bias[c0], bb1 = bias[c0 + 16], bb2 = bias[c0 + 32], bb3 = bias[c0 + 48];

    for (int ni = 0; ni < 4; ni++) {
        int nl = 4 * w + ni;
        int nd = d0 + nl;
        if (nd >= N) break;
        int eL = ofs[nl] - s0;
        int pd = pds[nl];
        int K = pd >> 1;           // per-half run; multiple of 8
        int be = eL + half * K;    // contiguous half

        f2_t accA01 = (f2_t){0.f, 0.f}, accA23 = (f2_t){0.f, 0.f};
        f2_t accB01 = (f2_t){0.f, 0.f}, accB23 = (f2_t){0.f, 0.f};

        if (eL + pd <= scnt) {
#define IDX_L(e) sidx[e]
            for (int i = 0; i < K; i += 8) AGG_ROUND(IDX_L)
#undef IDX_L
        } else {
            const int* gp = csr + s0;   // rare: slice > 768 (staging overflow)
#define IDX_G(e) gp[e]
            for (int i = 0; i < K; i += 8) AGG_ROUND(IDX_G)
#undef IDX_G
        }

        float a0 = accA01[0] + accB01[0];
        float a1 = accA01[1] + accB01[1];
        float a2 = accA23[0] + accB23[0];
        float a3 = accA23[1] + accB23[1];
        a0 += __shfl_xor(a0, 32);
        a1 += __shfl_xor(a1, 32);
        a2 += __shfl_xor(a2, 32);
        a3 += __shfl_xor(a3, 32);

        if (!half) {
            float dv = dv16[nl];
            float o0 = a0 * dv + bb0;
            float o1 = a1 * dv + bb1;
            float o2 = a2 * dv + bb2;
            float o3 = a3 * dv + bb3;
            if (elu) {
                o0 = o0 > 0.f ? o0 : __expf(o0) - 1.f;
                o1 = o1 > 0.f ? o1 : __expf(o1) - 1.f;
                o2 = o2 > 0.f ? o2 : __expf(o2) - 1.f;
                o3 = o3 > 0.f ? o3 : __expf(o3) - 1.f;
            }
            unsigned int p0 = (unsigned int)f2b(o0) | ((unsigned int)f2b(o1) << 16);
            unsigned int p1 = (unsigned int)f2b(o2) | ((unsigned int)f2b(o3) << 16);
            *(uint2*)&Out[(size_t)nd * DH + (l5 << 2)] = make_uint2(p0, p1);
        }
    }
}

// ---------- Mean pool: wave-per-row streaming, (G x 32) blocks, bf16 input ----------
// Input rows are in permuted byte order; Gsum stays permuted (k_head fixes).
__global__ __launch_bounds__(256) void k_pool(const unsigned int* __restrict__ H32,
                                              const int* __restrict__ batch,
                                              float* __restrict__ Gsum,
                                              int* __restrict__ cnts, int N) {
    int g = blockIdx.x;
    int p = blockIdx.y;
    int t = threadIdx.x;
    int lane = t & 63;
    int rg = t >> 6;  // wave 0..3
    int lo = 0, hi = N;
    while (lo < hi) { int m = (lo + hi) >> 1; if (batch[m] < g) lo = m + 1; else hi = m; }
    int s = lo;
    hi = N;
    while (lo < hi) { int m = (lo + hi) >> 1; if (batch[m] < g + 1) lo = m + 1; else hi = m; }
    int e = lo;
    int len = e - s;
    int parts = (int)gridDim.y;
    int chunk = (len + parts - 1) / parts;
    int i0 = s + p * chunk;
    int i1 = min(i0 + chunk, e);
    float a0 = 0.f, a1 = 0.f;
    for (int i = i0 + rg; i < i1; i += 4) {
        unsigned int v = H32[(size_t)i * 64 + lane];
        a0 += b2f((unsigned short)(v & 0xffffu));
        a1 += b2f((unsigned short)(v >> 16));
    }
    __shared__ float ps[4][DH];
    ps[rg][lane * 2] = a0;
    ps[rg][lane * 2 + 1] = a1;
    __syncthreads();
    if (t < DH) {
        float v = ps[0][t] + ps[1][t] + ps[2][t] + ps[3][t];
        atomicAdd(&Gsum[g * DH + t], v);
    }
    if (p == 0 && t == 0) cnts[g] = len;
}

// ---------- MLP head + log_softmax (un-permutes Gsum on load) ----------
__global__ __launch_bounds__(64) void k_head(const float* __restrict__ Gsum,
                                             const int* __restrict__ cnts,
                                             const float* __restrict__ W1,
                                             const float* __restrict__ b1,
                                             const float* __restrict__ W2,
                                             const float* __restrict__ b2,
                                             float* __restrict__ out) {
    int g = blockIdx.x;
    int t = threadIdx.x;
    __shared__ float gv[DH];
    __shared__ float mid[20];
    __shared__ float o[10];
    float inv = 1.f / fmaxf((float)cnts[g], 1.f);
    for (int i = t; i < DH; i += 64) {
        int c = ((i & 7) << 4) | (i >> 3);   // true col of permuted pos i
        gv[c] = Gsum[g * DH + i] * inv;
    }
    __syncthreads();
    if (t < 20) {
        float a = b1[t];
        for (int k = 0; k < DH; k++) a += gv[k] * W1[k * 20 + t];
        mid[t] = fmaxf(a, 0.f);
    }
    __syncthreads();
    if (t < 10) {
        float a = b2[t];
        for (int k = 0; k < 20; k++) a += mid[k] * W2[k * 10 + t];
        o[t] = a;
    }
    __syncthreads();
    if (t == 0) {
        float m = -1e30f;
        for (int j = 0; j < 10; j++) m = fmaxf(m, o[j]);
        float ssum = 0.f;
        for (int j = 0; j < 10; j++) ssum += expf(o[j] - m);
        float l = logf(ssum);
        for (int j = 0; j < 10; j++) out[g * 10 + j] = o[j] - m - l;
    }
}

extern "C" void kernel_launch(void* const* d_in, const int* in_sizes, int n_in,
                              void* d_out, int out_size, void* d_ws, size_t ws_size,
                              hipStream_t stream) {
    const float* x    = (const float*)d_in[0];
    const int*   ei   = (const int*)d_in[1];
    const int*   batch= (const int*)d_in[2];
    const float* W1   = (const float*)d_in[3];
    const float* b1   = (const float*)d_in[4];
    const float* W2   = (const float*)d_in[5];
    const float* b2   = (const float*)d_in[6];
    const float* fc1W = (const float*)d_in[7];
    const float* fc1b = (const float*)d_in[8];
    const float* fc2W = (const float*)d_in[9];
    const float* fc2b = (const float*)d_in[10];
    float* out = (float*)d_out;

    int N = in_sizes[0] / DH;     // 100000
    int E = in_sizes[1] / 2;      // 1600000
    int G = out_size / 10;        // 64
    int nbuck = (N + 511) >> 9;   // 196

    char* p = (char*)d_ws;
    auto alloc = [&](size_t bytes) {
        char* r = p;
        p += (bytes + 255) & ~(size_t)255;
        return r;
    };
    // t8 not aliased with pairs (ws 256MB, we use ~80MB) -> W-prep is fully
    // independent and rides along in the k_bucket launch.
    unsigned int*   pairs = (unsigned int*)alloc((size_t)nbuck * BCAP * 4);
    unsigned char*  t8    = (unsigned char*)alloc((size_t)(N + 1) * DH); // +1: zero row
    unsigned short* a1 = (unsigned short*)alloc((size_t)N * DH * 2); // bf16 act (both layers)
    int*   csr  = (int*)alloc((size_t)nbuck * BCAP * 4);             // bucket-strided, padded
    int*   off  = (int*)alloc((size_t)N * 4);
    int*   dpd  = (int*)alloc((size_t)N * 4);
    float* dinv = (float*)alloc((size_t)N * 4);
    unsigned short* Wt1 = (unsigned short*)alloc(DH * DH * 2);
    unsigned short* Wt2 = (unsigned short*)alloc(DH * DH * 2);
    float* Gsum = (float*)alloc((size_t)G * DH * 4);
    int*   bcur = (int*)alloc(256 * 16 * 4);
    int*   cnts = (int*)alloc((size_t)G * 4);

    const int* row = ei;       // message source
    const int* col = ei + E;   // aggregation target

    (void)hipMemsetAsync(Gsum, 0, (size_t)G * DH * 4 + 256 * 16 * 4, stream);

    const int chunk = 2048;
    int ablocks = (E + chunk - 1) / chunk;  // 782
    k_bucket<<<ablocks + 128, 256, 0, stream>>>(row, col, E, nbuck, chunk, ablocks,
                                                pairs, bcur, W1, W2, Wt1, Wt2,
                                                (unsigned int*)(t8 + (size_t)N * DH));
    k_build<<<nbuck, 512, 0, stream>>>(pairs, bcur, nbuck, N, off, dpd, dinv, csr);

    int gblocks = (N + 63) / 64;
    int mblocks = (N + 15) / 16;  // 6250
    // layer 1
    k_gemm_mfma<<<gblocks, 256, 0, stream>>>(x, 0, Wt1, dinv, t8, N);
    k_agg<<<mblocks, 256, 0, stream>>>(t8, a1, dinv, off, dpd, csr, b1, 1, N);
    // layer 2
    k_gemm_mfma<<<gblocks, 256, 0, stream>>>(a1, 1, Wt2, dinv, t8, N);
    k_agg<<<mblocks, 256, 0, stream>>>(t8, a1, dinv, off, dpd, csr, b2, 0, N);

    dim3 pg(G, 32);
    k_pool<<<pg, 256, 0, stream>>>((const unsigned int*)a1, batch, Gsum, cnts, N);
    k_head<<<G, 64, 0, stream>>>(Gsum, cnts, fc1W, fc1b, fc2W, fc2b, out);
}